// Round 4
// baseline (670.500 us; speedup 1.0000x reference)
//
#include <hip/hip_runtime.h>
#include <math.h>

#define HEAD_DIM   128
#define NUM_Q_HEAD 32
#define NUM_KV_HEAD 8
#define SEQLEN_Q   4096
#define SEQLEN_KV  4096
#define BLOCK_Q    128
#define BLOCK_KV   128
#define WINDOW     512
#define SOFTCAP    50.0f
#define EPSV       1e-5f
#define NB         4

#define QROWS  32
#define ZSPLIT (BLOCK_Q / QROWS)               // 4
#define NATT   (NB * NUM_Q_HEAD * ZSPLIT)      // 512 attention blocks

#define O_FLOATS   (NB * SEQLEN_Q * NUM_Q_HEAD * HEAD_DIM)  // 67,108,864
#define LSE_FLOATS (NB * NUM_Q_HEAD * SEQLEN_Q)             // 524,288
#define O4N   (O_FLOATS / 4)                                // 16,777,216
#define L4N   (LSE_FLOATS / 4)                              // 131,072

// Copy kernel geometry: 2048 blocks * 256 threads = 524,288 threads
// O4N = 524,288 * 32 exactly -> 32 float4/thread, no bounds checks.
#define GRID_COPY 2048
#define GSIZE     ((long long)GRID_COPY * 256)   // 524,288

// Kernel 1: bulk copy of global_o and global_lse into out (ALL rows,
// including the 128 rows the attention kernel will overwrite afterwards).
// Textbook m13-shaped stream: grid-stride float4, no LDS, no branches,
// regular cached loads/stores, 8 blocks/CU resident, 4-wide batched unroll.
__global__ __launch_bounds__(256) void bulk_copy(
    const float* __restrict__ gog, const float* __restrict__ glse,
    float* __restrict__ out)
{
    const float4* so = (const float4*)gog;
    const float4* sl = (const float4*)glse;
    float4* d0 = (float4*)out;
    float4* dL = (float4*)(out + (long long)O_FLOATS);

    const long long g = (long long)blockIdx.x * 256 + threadIdx.x;

#pragma unroll
    for (int it = 0; it < 8; ++it) {
        const long long i = g + (long long)it * (GSIZE * 4);
        float4 a = so[i];
        float4 b = so[i + GSIZE];
        float4 c = so[i + 2 * GSIZE];
        float4 d = so[i + 3 * GSIZE];
        d0[i]             = a;
        d0[i + GSIZE]     = b;
        d0[i + 2 * GSIZE] = c;
        d0[i + 3 * GSIZE] = d;
    }
    if (g < (long long)L4N) dL[g] = sl[g];
}

// Kernel 2: attention update of the 128 block rows (+ lse). Runs after
// bulk_copy on the same stream, so it simply overwrites its rows in out.
__global__ __launch_bounds__(256, 8) void osw_attn(
    const float* __restrict__ qg, const float* __restrict__ kg_,
    const float* __restrict__ vg, const float* __restrict__ gog,
    const float* __restrict__ glse, const float* __restrict__ gq,
    const float* __restrict__ gk, const int* __restrict__ pbq,
    const int* __restrict__ pbkv, float* __restrict__ out)
{
    // buf: first qn2 = q * inv_rms_q * gq * gk * SCALE, later p[q][k]
    __shared__ float buf[QROWS][HEAD_DIM + 4];
    __shared__ float invks[BLOCK_KV];            // 1/rms per K row
    __shared__ float colds[QROWS];
    __shared__ float cblks[QROWS];

    const int tid  = threadIdx.x;
    const int row0 = pbq[0] * BLOCK_Q;

    const int ab = blockIdx.x;
    const int b  = ab >> 7;          // 32 heads * 4 z per batch
    const int h  = (ab >> 2) & 31;
    const int z  = ab & 3;
    const int qo = z * QROWS;
    const int kh = h >> 2;           // GQA: rep = 4
    const int blkkv = pbkv[0];
    const float scale = 0.088388347648318447f;  // 1/sqrt(128)

    // Stage 1: inverse RMS of each K row (raw K consumed later; invk applied per score)
    {
        const int r = tid >> 1, half = tid & 1;
        const float* kr = kg_ + (((long long)b * BLOCK_KV + r) * NUM_KV_HEAD + kh) * HEAD_DIM + half * 64;
        float ss = 0.f;
#pragma unroll
        for (int i = 0; i < 16; ++i) {
            float4 x = ((const float4*)kr)[i];
            ss = fmaf(x.x, x.x, ss); ss = fmaf(x.y, x.y, ss);
            ss = fmaf(x.z, x.z, ss); ss = fmaf(x.w, x.w, ss);
        }
        ss += __shfl_xor(ss, 1);
        if (half == 0) invks[r] = rsqrtf(ss * (1.0f / HEAD_DIM) + EPSV);
    }

    // Stage 2: buf = q * inv_rms_q * gq * gk(kv-head) * SCALE (folds both gammas + scale)
    {
        const int r = tid >> 3, part = tid & 7;
        const float* qr = qg + (((long long)b * BLOCK_Q + qo + r) * NUM_Q_HEAD + h) * HEAD_DIM + part * 16;
        float4 xv[4];
        float ss = 0.f;
#pragma unroll
        for (int i = 0; i < 4; ++i) {
            xv[i] = ((const float4*)qr)[i];
            ss = fmaf(xv[i].x, xv[i].x, ss); ss = fmaf(xv[i].y, xv[i].y, ss);
            ss = fmaf(xv[i].z, xv[i].z, ss); ss = fmaf(xv[i].w, xv[i].w, ss);
        }
        ss += __shfl_xor(ss, 1);
        ss += __shfl_xor(ss, 2);
        ss += __shfl_xor(ss, 4);
        const float inv = rsqrtf(ss * (1.0f / HEAD_DIM) + EPSV) * scale;
        const float* gqp = gq + h * HEAD_DIM + part * 16;
        const float* gkp = gk + kh * HEAD_DIM + part * 16;
#pragma unroll
        for (int i = 0; i < 4; ++i) {
            float4 a = ((const float4*)gqp)[i];
            float4 c = ((const float4*)gkp)[i];
            int d = part * 16 + i * 4;
            buf[r][d + 0] = xv[i].x * inv * a.x * c.x;
            buf[r][d + 1] = xv[i].y * inv * a.y * c.y;
            buf[r][d + 2] = xv[i].z * inv * a.z * c.z;
            buf[r][d + 3] = xv[i].w * inv * a.w * c.w;
        }
    }
    __syncthreads();

    const int qrow = tid >> 3;   // 0..31
    const int kg   = tid & 7;    // 8 lanes per q row
    const int qi   = row0 + qo + qrow;

    // Stage 3: scores = invk[k] * (qn2 . K_raw), cap, mask, softmax stats, merge coeffs
    {
        float acc[16];
#pragma unroll
        for (int j = 0; j < 16; ++j) acc[j] = 0.f;
        const float* kbase = kg_ + (((long long)b * BLOCK_KV + kg * 16) * NUM_KV_HEAD + kh) * HEAD_DIM;
        for (int d4 = 0; d4 < HEAD_DIM; d4 += 4) {
            const float4 qf = *(const float4*)&buf[qrow][d4];
#pragma unroll
            for (int j = 0; j < 16; ++j) {
                const float4 kf = *(const float4*)(kbase + j * (NUM_KV_HEAD * HEAD_DIM) + d4);
                acc[j] = fmaf(qf.x, kf.x, acc[j]);
                acc[j] = fmaf(qf.y, kf.y, acc[j]);
                acc[j] = fmaf(qf.z, kf.z, acc[j]);
                acc[j] = fmaf(qf.w, kf.w, acc[j]);
            }
        }
        const int diag = qi + (SEQLEN_KV - SEQLEN_Q);
        float sv[16];
        float m = -INFINITY;
#pragma unroll
        for (int j = 0; j < 16; ++j) {
            const int kj = blkkv * BLOCK_KV + kg * 16 + j;
            float logit  = acc[j] * invks[kg * 16 + j];
            float capped = SOFTCAP * tanhf(logit * (1.0f / SOFTCAP));
            bool allowed = (kj <= diag) && (kj >= diag - WINDOW) &&
                           (qi < SEQLEN_Q) && (kj < SEQLEN_KV);
            sv[j] = allowed ? capped : -INFINITY;
            m = fmaxf(m, sv[j]);
        }
        m = fmaxf(m, __shfl_xor(m, 1));
        m = fmaxf(m, __shfl_xor(m, 2));
        m = fmaxf(m, __shfl_xor(m, 4));
        float ev[16];
        float l = 0.f;
#pragma unroll
        for (int j = 0; j < 16; ++j) {
            ev[j] = (sv[j] > -INFINITY) ? expf(sv[j] - m) : 0.f;
            l += ev[j];
        }
        l += __shfl_xor(l, 1);
        l += __shfl_xor(l, 2);
        l += __shfl_xor(l, 4);
        const float lse_blk = (l > 0.f) ? (m + logf(l)) : -INFINITY;
        const float rinv    = (l > 0.f) ? (1.0f / l) : 0.f;

        // All qn2 reads done by every thread before this barrier; buf is
        // then reused as the probability matrix.
        __syncthreads();
#pragma unroll
        for (int j = 0; j < 16; ++j) buf[qrow][kg * 16 + j] = ev[j] * rinv;

        // online merge with running stats
        const long long lidx = ((long long)b * NUM_Q_HEAD + h) * SEQLEN_Q + qi;
        const float lse_old = glse[lidx];
        float lse_new;
        if (lse_blk == -INFINITY)      lse_new = lse_old;
        else if (lse_old == -INFINITY) lse_new = lse_blk;
        else {
            const float mx = fmaxf(lse_old, lse_blk);
            lse_new = mx + log1pf(expf(-fabsf(lse_old - lse_blk)));
        }
        const float co = (lse_old == -INFINITY || lse_new == -INFINITY) ? 0.f : expf(lse_old - lse_new);
        const float cb = (lse_blk == -INFINITY || lse_new == -INFINITY) ? 0.f : expf(lse_blk - lse_new);
        if (kg == 0) {
            colds[qrow] = co;
            cblks[qrow] = cb;
            out[(long long)O_FLOATS + lidx] = lse_new;
        }
    }
    __syncthreads();

    // Stage 4: O = c_old * O_old + c_blk * (P @ V); write merged block rows
    {
        const int dg = tid & 7;      // 16 output dims per thread
        const float* vbase = vg + ((long long)b * BLOCK_KV * NUM_KV_HEAD + kh) * HEAD_DIM + dg * 16;
        float4 a0 = make_float4(0.f, 0.f, 0.f, 0.f);
        float4 a1 = a0, a2 = a0, a3 = a0;
#pragma unroll 2
        for (int kk = 0; kk < BLOCK_KV; ++kk) {
            const float p = buf[qrow][kk];
            const float4* vr = (const float4*)(vbase + (long long)kk * (NUM_KV_HEAD * HEAD_DIM));
            float4 v0 = vr[0], v1 = vr[1], v2 = vr[2], v3 = vr[3];
            a0.x = fmaf(p, v0.x, a0.x); a0.y = fmaf(p, v0.y, a0.y);
            a0.z = fmaf(p, v0.z, a0.z); a0.w = fmaf(p, v0.w, a0.w);
            a1.x = fmaf(p, v1.x, a1.x); a1.y = fmaf(p, v1.y, a1.y);
            a1.z = fmaf(p, v1.z, a1.z); a1.w = fmaf(p, v1.w, a1.w);
            a2.x = fmaf(p, v2.x, a2.x); a2.y = fmaf(p, v2.y, a2.y);
            a2.z = fmaf(p, v2.z, a2.z); a2.w = fmaf(p, v2.w, a2.w);
            a3.x = fmaf(p, v3.x, a3.x); a3.y = fmaf(p, v3.y, a3.y);
            a3.z = fmaf(p, v3.z, a3.z); a3.w = fmaf(p, v3.w, a3.w);
        }
        const long long obase = (((long long)b * SEQLEN_Q + qi) * NUM_Q_HEAD + h) * HEAD_DIM + dg * 16;
        const float co = colds[qrow], cb = cblks[qrow];
        const float4* oo = (const float4*)(gog + obase);
        float4*       od = (float4*)(out + obase);
        float4 q0 = oo[0], q1 = oo[1], q2 = oo[2], q3 = oo[3];
        float4 r0, r1, r2, r3;
        r0.x = fmaf(co, q0.x, cb * a0.x); r0.y = fmaf(co, q0.y, cb * a0.y);
        r0.z = fmaf(co, q0.z, cb * a0.z); r0.w = fmaf(co, q0.w, cb * a0.w);
        r1.x = fmaf(co, q1.x, cb * a1.x); r1.y = fmaf(co, q1.y, cb * a1.y);
        r1.z = fmaf(co, q1.z, cb * a1.z); r1.w = fmaf(co, q1.w, cb * a1.w);
        r2.x = fmaf(co, q2.x, cb * a2.x); r2.y = fmaf(co, q2.y, cb * a2.y);
        r2.z = fmaf(co, q2.z, cb * a2.z); r2.w = fmaf(co, q2.w, cb * a2.w);
        r3.x = fmaf(co, q3.x, cb * a3.x); r3.y = fmaf(co, q3.y, cb * a3.y);
        r3.z = fmaf(co, q3.z, cb * a3.z); r3.w = fmaf(co, q3.w, cb * a3.w);
        od[0] = r0; od[1] = r1; od[2] = r2; od[3] = r3;
    }
}

extern "C" void kernel_launch(void* const* d_in, const int* in_sizes, int n_in,
                              void* d_out, int out_size, void* d_ws, size_t ws_size,
                              hipStream_t stream) {
    const float* q   = (const float*)d_in[0];
    const float* k   = (const float*)d_in[1];
    const float* v   = (const float*)d_in[2];
    const float* go  = (const float*)d_in[3];
    const float* gl  = (const float*)d_in[4];
    const float* gq  = (const float*)d_in[5];
    const float* gk  = (const float*)d_in[6];
    const int*   bq  = (const int*)d_in[7];
    const int*   bkv = (const int*)d_in[8];
    float* out = (float*)d_out;

    // 1) full copy of global_o / global_lse into out (all rows)
    bulk_copy<<<dim3(GRID_COPY), dim3(256), 0, stream>>>(go, gl, out);
    // 2) attention update overwrites its 128 rows (stream-ordered after copy)
    osw_attn<<<dim3(NATT), dim3(256), 0, stream>>>(q, k, v, go, gl, gq, gk, bq, bkv, out);
}

// Round 5
// 532.716 us; speedup vs baseline: 1.2586x; 1.2586x over previous
//
#include <hip/hip_runtime.h>
#include <math.h>

#define HEAD_DIM   128
#define NUM_Q_HEAD 32
#define NUM_KV_HEAD 8
#define SEQLEN_Q   4096
#define SEQLEN_KV  4096
#define BLOCK_Q    128
#define BLOCK_KV   128
#define WINDOW     512
#define SOFTCAP    50.0f
#define EPSV       1e-5f
#define NB         4

#define QROWS  32
#define ZSPLIT (BLOCK_Q / QROWS)               // 4
#define NATT   (NB * NUM_Q_HEAD * ZSPLIT)      // 512 attention blocks

#define O_FLOATS   (NB * SEQLEN_Q * NUM_Q_HEAD * HEAD_DIM)  // 67,108,864
#define LSE_FLOATS (NB * NUM_Q_HEAD * SEQLEN_Q)             // 524,288
#define O4N   (O_FLOATS / 4)                                // 16,777,216
#define L4N   (LSE_FLOATS / 4)                              // 131,072

// Copy kernel geometry: 2048 blocks * 256 threads = 524,288 threads
#define GRID_COPY 2048
#define GSIZE     ((long long)GRID_COPY * 256)   // 524,288

// Kernel 1: bulk copy of global_o and global_lse into out (ALL rows,
// including the 128 rows the attention kernel will overwrite afterwards).
__global__ __launch_bounds__(256) void bulk_copy(
    const float* __restrict__ gog, const float* __restrict__ glse,
    float* __restrict__ out)
{
    const float4* so = (const float4*)gog;
    const float4* sl = (const float4*)glse;
    float4* d0 = (float4*)out;
    float4* dL = (float4*)(out + (long long)O_FLOATS);

    const long long g = (long long)blockIdx.x * 256 + threadIdx.x;

#pragma unroll
    for (int it = 0; it < 8; ++it) {
        const long long i = g + (long long)it * (GSIZE * 4);
        float4 a = so[i];
        float4 b = so[i + GSIZE];
        float4 c = so[i + 2 * GSIZE];
        float4 d = so[i + 3 * GSIZE];
        d0[i]             = a;
        d0[i + GSIZE]     = b;
        d0[i + 2 * GSIZE] = c;
        d0[i + 3 * GSIZE] = d;
    }
    if (g < (long long)L4N) dL[g] = sl[g];
}

// Kernel 2: attention update. LDS-staged K/V (half tiles of 64 rows), all
// inner-loop operands come from LDS with bank-conflict-free mappings:
//  - scores: thread (qrow=tid>>3, l8=tid&7) owns k-rows {8j+l8}: LDS bank
//    4*l8 spread covers all 32 banks; 8 qrow lanes broadcast.
//  - PV: thread owns dims {32i+4*l8}: bank 4*l8 spread, conflict-free.
//  - +4 float row pad on all tiles.
// invk is folded into staged K, so logits come straight out of the FMA loop.
// Merge coeffs stay in registers (same thread mapping for scores and PV).
__global__ __launch_bounds__(256, 2) void osw_attn(
    const float* __restrict__ qg, const float* __restrict__ kg_,
    const float* __restrict__ vg, const float* __restrict__ gog,
    const float* __restrict__ glse, const float* __restrict__ gq,
    const float* __restrict__ gk, const int* __restrict__ pbq,
    const int* __restrict__ pbkv, float* __restrict__ out)
{
    __shared__ float kv[64][HEAD_DIM + 4];       // K half-tile, then V half-tile
    __shared__ float buf[QROWS][HEAD_DIM + 4];   // qn2, then p[q][k]
    __shared__ float invks[BLOCK_KV];            // 1/rms per K row

    const int tid  = threadIdx.x;
    const int row0 = pbq[0] * BLOCK_Q;

    const int ab = blockIdx.x;
    const int b  = ab >> 7;          // 32 heads * 4 z per batch
    const int h  = (ab >> 2) & 31;
    const int z  = ab & 3;
    const int qo = z * QROWS;
    const int kh = h >> 2;           // GQA: rep = 4
    const int blkkv = pbkv[0];
    const float scale = 0.088388347648318447f;  // 1/sqrt(128)

    // Stage 1: inverse RMS of each K row
    {
        const int r = tid >> 1, half = tid & 1;
        const float* kr = kg_ + (((long long)b * BLOCK_KV + r) * NUM_KV_HEAD + kh) * HEAD_DIM + half * 64;
        float ss = 0.f;
#pragma unroll
        for (int i = 0; i < 16; ++i) {
            float4 x = ((const float4*)kr)[i];
            ss = fmaf(x.x, x.x, ss); ss = fmaf(x.y, x.y, ss);
            ss = fmaf(x.z, x.z, ss); ss = fmaf(x.w, x.w, ss);
        }
        ss += __shfl_xor(ss, 1);
        if (half == 0) invks[r] = rsqrtf(ss * (1.0f / HEAD_DIM) + EPSV);
    }

    // Stage 2: buf = q * inv_rms_q * gq * gk(kv-head) * SCALE
    {
        const int r = tid >> 3, part = tid & 7;
        const float* qr = qg + (((long long)b * BLOCK_Q + qo + r) * NUM_Q_HEAD + h) * HEAD_DIM + part * 16;
        float4 xv[4];
        float ss = 0.f;
#pragma unroll
        for (int i = 0; i < 4; ++i) {
            xv[i] = ((const float4*)qr)[i];
            ss = fmaf(xv[i].x, xv[i].x, ss); ss = fmaf(xv[i].y, xv[i].y, ss);
            ss = fmaf(xv[i].z, xv[i].z, ss); ss = fmaf(xv[i].w, xv[i].w, ss);
        }
        ss += __shfl_xor(ss, 1);
        ss += __shfl_xor(ss, 2);
        ss += __shfl_xor(ss, 4);
        const float inv = rsqrtf(ss * (1.0f / HEAD_DIM) + EPSV) * scale;
        const float* gqp = gq + h * HEAD_DIM + part * 16;
        const float* gkp = gk + kh * HEAD_DIM + part * 16;
#pragma unroll
        for (int i = 0; i < 4; ++i) {
            float4 a = ((const float4*)gqp)[i];
            float4 c = ((const float4*)gkp)[i];
            int d = part * 16 + i * 4;
            buf[r][d + 0] = xv[i].x * inv * a.x * c.x;
            buf[r][d + 1] = xv[i].y * inv * a.y * c.y;
            buf[r][d + 2] = xv[i].z * inv * a.z * c.z;
            buf[r][d + 3] = xv[i].w * inv * a.w * c.w;
        }
    }
    __syncthreads();   // invks + qn2 ready

    const int qrow = tid >> 3;   // 0..31
    const int l8   = tid & 7;
    const int qi   = row0 + qo + qrow;
    const int diag = qi + (SEQLEN_KV - SEQLEN_Q);

    // staging mapping: 4 threads per row, 32 floats each (coalesced, 2-way-free writes)
    const int sr  = tid >> 2;          // 0..63
    const int sc0 = (tid & 3) * 32;

    auto stage_k = [&](int half) {
        const int gr = half * 64 + sr;
        const float iv = invks[gr];
        const float* src = kg_ + (((long long)b * BLOCK_KV + gr) * NUM_KV_HEAD + kh) * HEAD_DIM + sc0;
#pragma unroll
        for (int i = 0; i < 8; ++i) {
            float4 x = ((const float4*)src)[i];
            float4 y; y.x = x.x * iv; y.y = x.y * iv; y.z = x.z * iv; y.w = x.w * iv;
            *(float4*)&kv[sr][sc0 + i * 4] = y;
        }
    };
    auto stage_v = [&](int half) {
        const int gr = half * 64 + sr;
        const float* src = vg + (((long long)b * BLOCK_KV + gr) * NUM_KV_HEAD + kh) * HEAD_DIM + sc0;
#pragma unroll
        for (int i = 0; i < 8; ++i)
            *(float4*)&kv[sr][sc0 + i * 4] = ((const float4*)src)[i];
    };
    // scores over the staged 64 k-rows; thread owns local rows {8j + l8}
    auto scores = [&](float (&acc8)[8]) {
        for (int d4 = 0; d4 < HEAD_DIM; d4 += 4) {
            const float4 qf = *(const float4*)&buf[qrow][d4];
#pragma unroll
            for (int j = 0; j < 8; ++j) {
                const float4 kf = *(const float4*)&kv[8 * j + l8][d4];
                acc8[j] = fmaf(qf.x, kf.x, acc8[j]);
                acc8[j] = fmaf(qf.y, kf.y, acc8[j]);
                acc8[j] = fmaf(qf.z, kf.z, acc8[j]);
                acc8[j] = fmaf(qf.w, kf.w, acc8[j]);
            }
        }
    };

    float accA[8] = {0.f, 0.f, 0.f, 0.f, 0.f, 0.f, 0.f, 0.f};
    float accB[8] = {0.f, 0.f, 0.f, 0.f, 0.f, 0.f, 0.f, 0.f};

    stage_k(0);
    __syncthreads();
    scores(accA);
    __syncthreads();          // K half0 reads done
    stage_k(1);
    __syncthreads();
    scores(accB);

    // softmax stats + merge coeffs (registers + 8-lane shuffles)
    float sv[16];
    float m = -INFINITY;
#pragma unroll
    for (int t = 0; t < 16; ++t) {
        const int kj = blkkv * BLOCK_KV + (t >> 3) * 64 + (t & 7) * 8 + l8;
        const float logit = (t < 8) ? accA[t & 7] : accB[t & 7];
        const float capped = SOFTCAP * tanhf(logit * (1.0f / SOFTCAP));
        const bool allowed = (kj <= diag) && (kj >= diag - WINDOW) &&
                             (qi < SEQLEN_Q) && (kj < SEQLEN_KV);
        sv[t] = allowed ? capped : -INFINITY;
        m = fmaxf(m, sv[t]);
    }
    m = fmaxf(m, __shfl_xor(m, 1));
    m = fmaxf(m, __shfl_xor(m, 2));
    m = fmaxf(m, __shfl_xor(m, 4));
    float ev[16];
    float l = 0.f;
#pragma unroll
    for (int t = 0; t < 16; ++t) {
        ev[t] = (sv[t] > -INFINITY) ? expf(sv[t] - m) : 0.f;
        l += ev[t];
    }
    l += __shfl_xor(l, 1);
    l += __shfl_xor(l, 2);
    l += __shfl_xor(l, 4);
    const float lse_blk = (l > 0.f) ? (m + logf(l)) : -INFINITY;
    const float rinv    = (l > 0.f) ? (1.0f / l) : 0.f;

    const long long lidx = ((long long)b * NUM_Q_HEAD + h) * SEQLEN_Q + qi;
    const float lse_old = glse[lidx];
    float lse_new;
    if (lse_blk == -INFINITY)      lse_new = lse_old;
    else if (lse_old == -INFINITY) lse_new = lse_blk;
    else {
        const float mx = fmaxf(lse_old, lse_blk);
        lse_new = mx + log1pf(expf(-fabsf(lse_old - lse_blk)));
    }
    const float co = (lse_old == -INFINITY || lse_new == -INFINITY) ? 0.f : expf(lse_old - lse_new);
    const float cb = (lse_blk == -INFINITY || lse_new == -INFINITY) ? 0.f : expf(lse_blk - lse_new);
    if (l8 == 0) out[(long long)O_FLOATS + lidx] = lse_new;

    __syncthreads();          // all reads of buf(qn2) and kv(K half1) complete

    // write p into buf (overwriting qn2) and stage V half0 (overwriting K)
#pragma unroll
    for (int t = 0; t < 16; ++t)
        buf[qrow][(t >> 3) * 64 + (t & 7) * 8 + l8] = ev[t] * rinv;
    stage_v(0);
    __syncthreads();          // p + V half0 ready

    float4 a[4];
#pragma unroll
    for (int i = 0; i < 4; ++i) a[i] = make_float4(0.f, 0.f, 0.f, 0.f);

    auto pv = [&](int half) {
#pragma unroll 4
        for (int kk = 0; kk < 64; ++kk) {
            const float p = buf[qrow][half * 64 + kk];
#pragma unroll
            for (int i = 0; i < 4; ++i) {
                const float4 v = *(const float4*)&kv[kk][i * 32 + l8 * 4];
                a[i].x = fmaf(p, v.x, a[i].x);
                a[i].y = fmaf(p, v.y, a[i].y);
                a[i].z = fmaf(p, v.z, a[i].z);
                a[i].w = fmaf(p, v.w, a[i].w);
            }
        }
    };
    pv(0);
    __syncthreads();          // V half0 reads done
    stage_v(1);
    __syncthreads();          // V half1 ready
    pv(1);

    // epilogue: O = co * O_old + cb * (P @ V); thread owns dims {32i + 4*l8}
    const long long obase = (((long long)b * SEQLEN_Q + qi) * NUM_Q_HEAD + h) * HEAD_DIM;
#pragma unroll
    for (int i = 0; i < 4; ++i) {
        const int d0 = i * 32 + l8 * 4;
        const float4 q4 = *(const float4*)(gog + obase + d0);
        float4 r;
        r.x = fmaf(co, q4.x, cb * a[i].x);
        r.y = fmaf(co, q4.y, cb * a[i].y);
        r.z = fmaf(co, q4.z, cb * a[i].z);
        r.w = fmaf(co, q4.w, cb * a[i].w);
        *(float4*)(out + obase + d0) = r;
    }
}

extern "C" void kernel_launch(void* const* d_in, const int* in_sizes, int n_in,
                              void* d_out, int out_size, void* d_ws, size_t ws_size,
                              hipStream_t stream) {
    const float* q   = (const float*)d_in[0];
    const float* k   = (const float*)d_in[1];
    const float* v   = (const float*)d_in[2];
    const float* go  = (const float*)d_in[3];
    const float* gl  = (const float*)d_in[4];
    const float* gq  = (const float*)d_in[5];
    const float* gk  = (const float*)d_in[6];
    const int*   bq  = (const int*)d_in[7];
    const int*   bkv = (const int*)d_in[8];
    float* out = (float*)d_out;

    // 1) full copy of global_o / global_lse into out (all rows)
    bulk_copy<<<dim3(GRID_COPY), dim3(256), 0, stream>>>(go, gl, out);
    // 2) attention update overwrites its 128 rows (stream-ordered after copy)
    osw_attn<<<dim3(NATT), dim3(256), 0, stream>>>(q, k, v, go, gl, gq, gk, bq, bkv, out);
}

// Round 6
// 522.999 us; speedup vs baseline: 1.2820x; 1.0186x over previous
//
#include <hip/hip_runtime.h>
#include <math.h>

#define HEAD_DIM   128
#define NUM_Q_HEAD 32
#define NUM_KV_HEAD 8
#define SEQLEN_Q   4096
#define SEQLEN_KV  4096
#define BLOCK_Q    128
#define BLOCK_KV   128
#define WINDOW     512
#define SOFTCAP    50.0f
#define EPSV       1e-5f
#define NB         4

#define QROWS  32
#define ZSPLIT (BLOCK_Q / QROWS)               // 4
#define NATT   (NB * NUM_Q_HEAD * ZSPLIT)      // 512 attention blocks
#define NCOPY  8192                            // copy blocks

#define O_FLOATS   (NB * SEQLEN_Q * NUM_Q_HEAD * HEAD_DIM)  // 67,108,864
#define LSE_FLOATS (NB * NUM_Q_HEAD * SEQLEN_Q)             // 524,288
#define O4N   (O_FLOATS / 4)                                // 16,777,216
#define L4N   (LSE_FLOATS / 4)                              // 131,072
#define TOT4  (O4N + L4N)

// One fused kernel, two roles with disjoint output regions:
//   blocks [0, NATT)          : LDS-staged attention update of 128 rows (+ lse)
//   blocks [NATT, NATT+NCOPY) : float4 copy of everything EXCEPT those rows
// Fusion overlaps the ~85 µs attention under the ~180 µs copy stream.
__global__ __launch_bounds__(256, 3) void osw_fused(
    const float* __restrict__ qg, const float* __restrict__ kg_,
    const float* __restrict__ vg, const float* __restrict__ gog,
    const float* __restrict__ glse, const float* __restrict__ gq,
    const float* __restrict__ gk, const int* __restrict__ pbq,
    const int* __restrict__ pbkv, float* __restrict__ out)
{
    __shared__ float kv[64][HEAD_DIM + 4];       // K half-tile, then V half-tile
    __shared__ float buf[QROWS][HEAD_DIM + 4];   // qn2, then p[q][k]
    __shared__ float invks[BLOCK_KV];            // 1/rms per K row

    const int tid  = threadIdx.x;
    const int row0 = pbq[0] * BLOCK_Q;

    if (blockIdx.x >= NATT) {
        // ---------------- copy role ----------------
        const long long stride = (long long)NCOPY * 256;
        const float4* so  = (const float4*)gog;
        const float4* sl  = (const float4*)glse;
        float4*       dst = (float4*)out;
        long long base = (long long)(blockIdx.x - NATT) * 256 + tid;
        for (; base < (long long)TOT4; base += stride * 4) {
            float4 val[4];
            bool   wr[4];
#pragma unroll
            for (int u = 0; u < 4; ++u) {
                long long idx = base + (long long)u * stride;
                wr[u] = false;
                if (idx < (long long)O4N) {
                    // o flat float idx = idx*4; seq row = (idx>>10) & 4095
                    int srow = (int)((idx >> 10) & 4095);
                    if ((unsigned)(srow - row0) >= (unsigned)BLOCK_Q) {
                        wr[u] = true; val[u] = so[idx];
                    }
                } else if (idx < (long long)TOT4) {
                    int li   = (int)(idx - O4N);
                    int spos = (li & 1023) << 2;   // seq position of this float4
                    if ((unsigned)(spos - row0) >= (unsigned)BLOCK_Q) {
                        wr[u] = true; val[u] = sl[li];
                    }
                }
            }
#pragma unroll
            for (int u = 0; u < 4; ++u)
                if (wr[u]) dst[base + (long long)u * stride] = val[u];
        }
        return;
    }

    // ---------------- attention role (round-5 LDS-staged version) ----------------
    const int ab = blockIdx.x;
    const int b  = ab >> 7;          // 32 heads * 4 z per batch
    const int h  = (ab >> 2) & 31;
    const int z  = ab & 3;
    const int qo = z * QROWS;
    const int kh = h >> 2;           // GQA: rep = 4
    const int blkkv = pbkv[0];
    const float scale = 0.088388347648318447f;  // 1/sqrt(128)

    // Stage 1: inverse RMS of each K row
    {
        const int r = tid >> 1, half = tid & 1;
        const float* kr = kg_ + (((long long)b * BLOCK_KV + r) * NUM_KV_HEAD + kh) * HEAD_DIM + half * 64;
        float ss = 0.f;
#pragma unroll
        for (int i = 0; i < 16; ++i) {
            float4 x = ((const float4*)kr)[i];
            ss = fmaf(x.x, x.x, ss); ss = fmaf(x.y, x.y, ss);
            ss = fmaf(x.z, x.z, ss); ss = fmaf(x.w, x.w, ss);
        }
        ss += __shfl_xor(ss, 1);
        if (half == 0) invks[r] = rsqrtf(ss * (1.0f / HEAD_DIM) + EPSV);
    }

    // Stage 2: buf = q * inv_rms_q * gq * gk(kv-head) * SCALE
    {
        const int r = tid >> 3, part = tid & 7;
        const float* qr = qg + (((long long)b * BLOCK_Q + qo + r) * NUM_Q_HEAD + h) * HEAD_DIM + part * 16;
        float4 xv[4];
        float ss = 0.f;
#pragma unroll
        for (int i = 0; i < 4; ++i) {
            xv[i] = ((const float4*)qr)[i];
            ss = fmaf(xv[i].x, xv[i].x, ss); ss = fmaf(xv[i].y, xv[i].y, ss);
            ss = fmaf(xv[i].z, xv[i].z, ss); ss = fmaf(xv[i].w, xv[i].w, ss);
        }
        ss += __shfl_xor(ss, 1);
        ss += __shfl_xor(ss, 2);
        ss += __shfl_xor(ss, 4);
        const float inv = rsqrtf(ss * (1.0f / HEAD_DIM) + EPSV) * scale;
        const float* gqp = gq + h * HEAD_DIM + part * 16;
        const float* gkp = gk + kh * HEAD_DIM + part * 16;
#pragma unroll
        for (int i = 0; i < 4; ++i) {
            float4 a = ((const float4*)gqp)[i];
            float4 c = ((const float4*)gkp)[i];
            int d = part * 16 + i * 4;
            buf[r][d + 0] = xv[i].x * inv * a.x * c.x;
            buf[r][d + 1] = xv[i].y * inv * a.y * c.y;
            buf[r][d + 2] = xv[i].z * inv * a.z * c.z;
            buf[r][d + 3] = xv[i].w * inv * a.w * c.w;
        }
    }
    __syncthreads();   // invks + qn2 ready

    const int qrow = tid >> 3;   // 0..31
    const int l8   = tid & 7;
    const int qi   = row0 + qo + qrow;
    const int diag = qi + (SEQLEN_KV - SEQLEN_Q);

    // staging mapping: 4 threads per row, 32 floats each
    const int sr  = tid >> 2;          // 0..63
    const int sc0 = (tid & 3) * 32;

    auto stage_k = [&](int half) {
        const int gr = half * 64 + sr;
        const float iv = invks[gr];
        const float* src = kg_ + (((long long)b * BLOCK_KV + gr) * NUM_KV_HEAD + kh) * HEAD_DIM + sc0;
#pragma unroll
        for (int i = 0; i < 8; ++i) {
            float4 x = ((const float4*)src)[i];
            float4 y; y.x = x.x * iv; y.y = x.y * iv; y.z = x.z * iv; y.w = x.w * iv;
            *(float4*)&kv[sr][sc0 + i * 4] = y;
        }
    };
    auto stage_v = [&](int half) {
        const int gr = half * 64 + sr;
        const float* src = vg + (((long long)b * BLOCK_KV + gr) * NUM_KV_HEAD + kh) * HEAD_DIM + sc0;
#pragma unroll
        for (int i = 0; i < 8; ++i)
            *(float4*)&kv[sr][sc0 + i * 4] = ((const float4*)src)[i];
    };
    auto scores = [&](float (&acc8)[8]) {
        for (int d4 = 0; d4 < HEAD_DIM; d4 += 4) {
            const float4 qf = *(const float4*)&buf[qrow][d4];
#pragma unroll
            for (int j = 0; j < 8; ++j) {
                const float4 kf = *(const float4*)&kv[8 * j + l8][d4];
                acc8[j] = fmaf(qf.x, kf.x, acc8[j]);
                acc8[j] = fmaf(qf.y, kf.y, acc8[j]);
                acc8[j] = fmaf(qf.z, kf.z, acc8[j]);
                acc8[j] = fmaf(qf.w, kf.w, acc8[j]);
            }
        }
    };

    float accA[8] = {0.f, 0.f, 0.f, 0.f, 0.f, 0.f, 0.f, 0.f};
    float accB[8] = {0.f, 0.f, 0.f, 0.f, 0.f, 0.f, 0.f, 0.f};

    stage_k(0);
    __syncthreads();
    scores(accA);
    __syncthreads();          // K half0 reads done
    stage_k(1);
    __syncthreads();
    scores(accB);

    // softmax stats + merge coeffs
    float sv[16];
    float m = -INFINITY;
#pragma unroll
    for (int t = 0; t < 16; ++t) {
        const int kj = blkkv * BLOCK_KV + (t >> 3) * 64 + (t & 7) * 8 + l8;
        const float logit = (t < 8) ? accA[t & 7] : accB[t & 7];
        const float capped = SOFTCAP * tanhf(logit * (1.0f / SOFTCAP));
        const bool allowed = (kj <= diag) && (kj >= diag - WINDOW) &&
                             (qi < SEQLEN_Q) && (kj < SEQLEN_KV);
        sv[t] = allowed ? capped : -INFINITY;
        m = fmaxf(m, sv[t]);
    }
    m = fmaxf(m, __shfl_xor(m, 1));
    m = fmaxf(m, __shfl_xor(m, 2));
    m = fmaxf(m, __shfl_xor(m, 4));
    float ev[16];
    float l = 0.f;
#pragma unroll
    for (int t = 0; t < 16; ++t) {
        ev[t] = (sv[t] > -INFINITY) ? expf(sv[t] - m) : 0.f;
        l += ev[t];
    }
    l += __shfl_xor(l, 1);
    l += __shfl_xor(l, 2);
    l += __shfl_xor(l, 4);
    const float lse_blk = (l > 0.f) ? (m + logf(l)) : -INFINITY;
    const float rinv    = (l > 0.f) ? (1.0f / l) : 0.f;

    const long long lidx = ((long long)b * NUM_Q_HEAD + h) * SEQLEN_Q + qi;
    const float lse_old = glse[lidx];
    float lse_new;
    if (lse_blk == -INFINITY)      lse_new = lse_old;
    else if (lse_old == -INFINITY) lse_new = lse_blk;
    else {
        const float mx = fmaxf(lse_old, lse_blk);
        lse_new = mx + log1pf(expf(-fabsf(lse_old - lse_blk)));
    }
    const float co = (lse_old == -INFINITY || lse_new == -INFINITY) ? 0.f : expf(lse_old - lse_new);
    const float cb = (lse_blk == -INFINITY || lse_new == -INFINITY) ? 0.f : expf(lse_blk - lse_new);
    if (l8 == 0) out[(long long)O_FLOATS + lidx] = lse_new;

    __syncthreads();          // all reads of buf(qn2) and kv(K half1) complete

    // write p into buf (overwriting qn2) and stage V half0 (overwriting K)
#pragma unroll
    for (int t = 0; t < 16; ++t)
        buf[qrow][(t >> 3) * 64 + (t & 7) * 8 + l8] = ev[t] * rinv;
    stage_v(0);
    __syncthreads();          // p + V half0 ready

    float4 a[4];
#pragma unroll
    for (int i = 0; i < 4; ++i) a[i] = make_float4(0.f, 0.f, 0.f, 0.f);

    auto pv = [&](int half) {
#pragma unroll 4
        for (int kk = 0; kk < 64; ++kk) {
            const float p = buf[qrow][half * 64 + kk];
#pragma unroll
            for (int i = 0; i < 4; ++i) {
                const float4 v = *(const float4*)&kv[kk][i * 32 + l8 * 4];
                a[i].x = fmaf(p, v.x, a[i].x);
                a[i].y = fmaf(p, v.y, a[i].y);
                a[i].z = fmaf(p, v.z, a[i].z);
                a[i].w = fmaf(p, v.w, a[i].w);
            }
        }
    };
    pv(0);
    __syncthreads();          // V half0 reads done
    stage_v(1);
    __syncthreads();          // V half1 ready
    pv(1);

    // epilogue: O = co * O_old + cb * (P @ V)
    const long long obase = (((long long)b * SEQLEN_Q + qi) * NUM_Q_HEAD + h) * HEAD_DIM;
#pragma unroll
    for (int i = 0; i < 4; ++i) {
        const int d0 = i * 32 + l8 * 4;
        const float4 q4 = *(const float4*)(gog + obase + d0);
        float4 r;
        r.x = fmaf(co, q4.x, cb * a[i].x);
        r.y = fmaf(co, q4.y, cb * a[i].y);
        r.z = fmaf(co, q4.z, cb * a[i].z);
        r.w = fmaf(co, q4.w, cb * a[i].w);
        *(float4*)(out + obase + d0) = r;
    }
}

extern "C" void kernel_launch(void* const* d_in, const int* in_sizes, int n_in,
                              void* d_out, int out_size, void* d_ws, size_t ws_size,
                              hipStream_t stream) {
    const float* q   = (const float*)d_in[0];
    const float* k   = (const float*)d_in[1];
    const float* v   = (const float*)d_in[2];
    const float* go  = (const float*)d_in[3];
    const float* gl  = (const float*)d_in[4];
    const float* gq  = (const float*)d_in[5];
    const float* gk  = (const float*)d_in[6];
    const int*   bq  = (const int*)d_in[7];
    const int*   bkv = (const int*)d_in[8];
    float* out = (float*)d_out;

    dim3 grid(NATT + NCOPY), block(256);
    osw_fused<<<grid, block, 0, stream>>>(q, k, v, go, gl, gq, gk, bq, bkv, out);
}